// Round 5
// baseline (280.975 us; speedup 1.0000x reference)
//
#include <hip/hip_runtime.h>
#include <math.h>

#define TB 8    // BATCH
#define TT 12   // T_IN
#define HV 32   // H_VEL

typedef float v2f __attribute__((ext_vector_type(2)));

// ---------- f64 velocity branch (cold path, rare; reads row from global) ----------
__device__ __noinline__ double vel_branch64(const float* x,
    const float* __restrict__ w1, const float* __restrict__ b1,
    const float* __restrict__ g,  const float* __restrict__ bn,
    const float* __restrict__ w2, float b2) {
  double s1 = 0.0, s2 = 0.0;
  for (int j = 0; j < HV; ++j) {
    double hj = (double)b1[j];
    for (int t = 0; t < TT; ++t) hj = fma((double)x[t], (double)w1[j*TT+t], hj);
    s1 += hj;
    s2 = fma(hj, hj, s2);
  }
  double mu  = s1 / (double)HV;
  double var = s2 / (double)HV - mu*mu;
  double inv = 1.0 / sqrt(var + 1e-5);
  double acc = (double)b2;
  for (int j = 0; j < HV; ++j) {
    double hj = (double)b1[j];
    for (int t = 0; t < TT; ++t) hj = fma((double)x[t], (double)w1[j*TT+t], hj);
    double yl = (hj - mu) * inv * (double)g[j] + (double)bn[j];
    if (yl < 0.0) yl = 0.0;
    acc = fma(yl, (double)w2[j], acc);
  }
  return 1.0 / (1.0 + exp(-acc));
}

// ---------- K_fold: precompute folded weight streams (one-time, 2 blocks) ----------
// Per branch br: stream[32][16] = {A_j[12], C_j, bn_j, w2_j, pad}, A_j = g_j*(W1_j - wbar),
// C_j = g_j*(b1_j - bbar); Mblk[144] = full symmetric M = mean_j a_j a_j^T (a = W1_j - wbar);
// Mblk[144..155] = r_t = 2*mean_j c_j a_jt; Mblk[156] = k = mean c^2.
__global__ void __launch_bounds__(256) k_fold(
    const float* __restrict__ v11_w, const float* __restrict__ v11_b,
    const float* __restrict__ ln11_g, const float* __restrict__ ln11_b,
    const float* __restrict__ v12_w,
    const float* __restrict__ v21_w, const float* __restrict__ v21_b,
    const float* __restrict__ ln21_g, const float* __restrict__ ln21_b,
    const float* __restrict__ v22_w,
    float* __restrict__ fold) {
  int br = blockIdx.x;
  const float* W1 = br ? v21_w : v11_w;
  const float* B1 = br ? v21_b : v11_b;
  const float* G  = br ? ln21_g : ln11_g;
  const float* BN = br ? ln21_b : ln11_b;
  const float* W2 = br ? v22_w : v12_w;
  float* stream = fold + br * 672;
  float* Mblk   = stream + 512;
  int tid = threadIdx.x;
  // every thread computes wbar/bbar redundantly (tiny one-time cost)
  float wbar[TT];
  for (int t = 0; t < TT; ++t) {
    float sw = 0.f;
    for (int j = 0; j < HV; ++j) sw += W1[j*TT + t];
    wbar[t] = sw * (1.f/HV);
  }
  float bbar = 0.f;
  for (int j = 0; j < HV; ++j) bbar += B1[j];
  bbar *= (1.f/HV);

  if (tid < HV) {
    int j = tid;
    float gj = G[j];
    for (int t = 0; t < TT; ++t) stream[j*16 + t] = gj * (W1[j*TT + t] - wbar[t]);
    stream[j*16 + 12] = gj * (B1[j] - bbar);
    stream[j*16 + 13] = BN[j];
    stream[j*16 + 14] = W2[j];
    stream[j*16 + 15] = 0.f;
  } else if (tid < 32 + 144) {
    int p = tid - 32, t = p / TT, s = p % TT;
    float m = 0.f;
    for (int j = 0; j < HV; ++j)
      m += (W1[j*TT + t] - wbar[t]) * (W1[j*TT + s] - wbar[s]);
    Mblk[p] = m * (1.f/HV);
  } else if (tid < 176 + 12) {
    int t = tid - 176;
    float rr = 0.f;
    for (int j = 0; j < HV; ++j) rr += (B1[j] - bbar) * (W1[j*TT + t] - wbar[t]);
    Mblk[144 + t] = rr * (2.f/HV);
  } else if (tid == 188) {
    float kk = 0.f;
    for (int j = 0; j < HV; ++j) { float c = B1[j] - bbar; kk += c*c; }
    Mblk[156] = kk * (1.f/HV);
  }
}

// ---------- K0: zero den+pred, block 0 reduces attention scalars ----------
__global__ void __launch_bounds__(256) k_zero_prep(
    float* __restrict__ den, float* __restrict__ pred, int nb,
    const float* __restrict__ attn_w, const float* __restrict__ ln2_g,
    const float* __restrict__ ln2_b, float* __restrict__ scal) {
  int idx = blockIdx.x * blockDim.x + threadIdx.x;
  for (int i = idx; i < nb; i += gridDim.x * blockDim.x) { den[i] = 0.f; pred[i] = 0.f; }
  if (blockIdx.x == 0) {
    __shared__ float sg[256], sb[256];
    float a = 0.f, b = 0.f;
    if (threadIdx.x < 129) {
      float w = attn_w[threadIdx.x];
      a = w * ln2_g[threadIdx.x];
      b = w * ln2_b[threadIdx.x];
    }
    sg[threadIdx.x] = a; sb[threadIdx.x] = b;
    __syncthreads();
    for (int s = 128; s > 0; s >>= 1) {
      if (threadIdx.x < s) { sg[threadIdx.x] += sg[threadIdx.x+s]; sb[threadIdx.x] += sb[threadIdx.x+s]; }
      __syncthreads();
    }
    if (threadIdx.x == 0) { scal[0] = sg[0]; scal[1] = sb[0]; }
  }
}

// ---------- K1: per-(node,batch) precompute {Sz, Sz2, p_src, p_dst} ----------
__global__ void __launch_bounds__(256, 2) k_node(
    const float* __restrict__ feature, const float* __restrict__ fc_w,
    const float* __restrict__ attn_w,  const float* __restrict__ ln2_g,
    float4* __restrict__ nodepre, int n_nodes) {
  int idx = blockIdx.x * blockDim.x + threadIdx.x;
  int total = n_nodes * TB;
  if (idx >= total) return;
  const float4* f4 = (const float4*)(feature + (size_t)idx * TT);
  float4 fa = f4[0], fb = f4[1], fcv = f4[2];
  v2f xv[6] = {{fa.x,fa.y},{fa.z,fa.w},{fb.x,fb.y},{fb.z,fb.w},{fcv.x,fcv.y},{fcv.z,fcv.w}};
  float q = 0.f, r = 0.f, ps = 0.f, pd = 0.f;
#pragma unroll 8
  for (int i = 0; i < 64; ++i) {
    v2f p = {0.f, 0.f};
#pragma unroll
    for (int k = 0; k < 6; ++k)
      p = __builtin_elementwise_fma(xv[k], *(const v2f*)(fc_w + i*TT + 2*k), p);
    float z = p.x + p.y;
    q += z;
    r  = fmaf(z, z, r);
    ps = fmaf(z, attn_w[i]      * ln2_g[i],      ps);
    pd = fmaf(z, attn_w[64 + i] * ln2_g[64 + i], pd);
  }
  nodepre[idx] = make_float4(q, r, ps, pd);
}

// ---------- K2: fused edge pass, 4 rows (same edge, 4 batch lanes) per thread ----------
__global__ void __launch_bounds__(256, 3) k_edge1(
    const float* __restrict__ upstream, const float* __restrict__ downstream,
    const float* __restrict__ feature,  const float* __restrict__ distance,
    const int* __restrict__ src, const int* __restrict__ dst,
    const float* __restrict__ attn_w, const float* __restrict__ ln2_g,
    const float* __restrict__ v11_w, const float* __restrict__ v11_b,
    const float* __restrict__ ln11_g, const float* __restrict__ ln11_b,
    const float* __restrict__ v12_w, const float* __restrict__ v12_b,
    const float* __restrict__ v21_w, const float* __restrict__ v21_b,
    const float* __restrict__ ln21_g, const float* __restrict__ ln21_b,
    const float* __restrict__ v22_w, const float* __restrict__ v22_b,
    const float* __restrict__ v3_w, const float* __restrict__ v3_b,
    const float* __restrict__ alpha,
    const float* __restrict__ fold,
    const float4* __restrict__ nodepre, const float* __restrict__ scal,
    float2* __restrict__ epbuf, float* __restrict__ den,
    int n_quads) {
  int idx = blockIdx.x * blockDim.x + threadIdx.x;
  if (idx >= n_quads) return;
  int e    = idx >> 1;
  int b0   = (idx & 1) * 4;
  int row0 = idx * 4;

  int s = src[e], d = dst[e];
  float dist = distance[e];
  float al   = alpha[e];
  float w3a = v3_w[0], w3b = v3_w[1];

  float ys[4];
  { float b3 = v3_b[0]; ys[0]=b3; ys[1]=b3; ys[2]=b3; ys[3]=b3; }

#pragma unroll 1
  for (int br = 0; br < 2; ++br) {
    const float* rows = br ? downstream : upstream;
    const float* st   = fold + br * 672;
    const float* Mb   = st + 512;
    float b2  = br ? v22_b[0] : v12_b[0];
    float w3v = br ? w3b : w3a;

    // load 4 rows (192B contiguous per thread)
    v2f xv[4][6];
    {
      const float4* r4 = (const float4*)(rows + (size_t)row0 * TT);
#pragma unroll
      for (int r = 0; r < 4; ++r) {
        float4 q0 = r4[r*3+0], q1 = r4[r*3+1], q2 = r4[r*3+2];
        xv[r][0] = (v2f){q0.x,q0.y}; xv[r][1] = (v2f){q0.z,q0.w};
        xv[r][2] = (v2f){q1.x,q1.y}; xv[r][3] = (v2f){q1.z,q1.w};
        xv[r][4] = (v2f){q2.x,q2.y}; xv[r][5] = (v2f){q2.z,q2.w};
      }
    }

    // ---- sigma phase: var = x^T M x + r.x + k (y_s = r_s + sum_t x_t M[t][s]) ----
    v2f y[4][6];
#pragma unroll
    for (int k = 0; k < 6; ++k) {
      v2f rv = *(const v2f*)(Mb + 144 + 2*k);
      y[0][k]=rv; y[1][k]=rv; y[2][k]=rv; y[3][k]=rv;
    }
#pragma unroll
    for (int t = 0; t < TT; ++t) {
      const float* mrow = Mb + t*TT;
#pragma unroll
      for (int k = 0; k < 6; ++k) {
        v2f mv = *(const v2f*)(mrow + 2*k);
#pragma unroll
        for (int r = 0; r < 4; ++r) {
          float xs = xv[r][t>>1][t&1];
          v2f xb = {xs, xs};
          y[r][k] = __builtin_elementwise_fma(xb, mv, y[r][k]);
        }
      }
    }
    float kc = Mb[156];
    float sig[4], iv[4], acc[4];
#pragma unroll
    for (int r = 0; r < 4; ++r) {
      v2f q = xv[r][0] * y[r][0];
#pragma unroll
      for (int k = 1; k < 6; ++k) q = __builtin_elementwise_fma(xv[r][k], y[r][k], q);
      float varp = q.x + q.y + kc + 1e-5f;
      float is = 1.f / sqrtf(varp);
      iv[r] = is; sig[r] = varp * is; acc[r] = 0.f;
    }

    // ---- j-stream: acc += relu(u_j + sig*bn_j) * w2_j, u never stored ----
#pragma unroll
    for (int j = 0; j < HV; ++j) {
      const float* sj = st + j*16;
      v2f a0 = *(const v2f*)(sj+0),  a1 = *(const v2f*)(sj+2),  a2 = *(const v2f*)(sj+4);
      v2f a3 = *(const v2f*)(sj+6),  a4 = *(const v2f*)(sj+8),  a5 = *(const v2f*)(sj+10);
      float Cj = sj[12], bnj = sj[13], wj2 = sj[14];
#pragma unroll
      for (int r = 0; r < 4; ++r) {
        v2f p = xv[r][0] * a0;
        p = __builtin_elementwise_fma(xv[r][1], a1, p);
        p = __builtin_elementwise_fma(xv[r][2], a2, p);
        p = __builtin_elementwise_fma(xv[r][3], a3, p);
        p = __builtin_elementwise_fma(xv[r][4], a4, p);
        p = __builtin_elementwise_fma(xv[r][5], a5, p);
        float u = p.x + p.y + Cj;
        float z = fmaf(sig[r], bnj, u);
        z = fmaxf(z, 0.f);
        acc[r] = fmaf(z, wj2, acc[r]);
      }
    }
#pragma unroll
    for (int r = 0; r < 4; ++r) {
      float val = fmaf(acc[r], iv[r], b2);
      float sg = 1.f / (1.f + __expf(-val));
      ys[r] = fmaf(sg, w3v, ys[r]);
    }
  }

  // ---- tail gathers (feature rows contiguous: 48 floats) ----
  float4 F[12];
  {
    const float4* f4 = (const float4*)(feature + ((size_t)s * TB + b0) * TT);
#pragma unroll
    for (int i = 0; i < 12; ++i) F[i] = f4[i];
  }
  float4 np_s[4], np_d[4];
#pragma unroll
  for (int r = 0; r < 4; ++r) {
    np_s[r] = nodepre[(size_t)s * TB + b0 + r];
    np_d[r] = nodepre[(size_t)d * TB + b0 + r];
  }
  float aw128 = attn_w[128] * ln2_g[128];
  float sc0 = scal[0], sc1 = scal[1];

  float exv[4], pev[4];
#pragma unroll
  for (int r = 0; r < 4; ++r) {
    float yv = ys[r];
    // softplus via hardware exp/log
    float v = fmaxf(yv, 0.f) + __logf(1.f + __expf(-fabsf(yv)));
    float tt  = dist / (v + 1e-5f);
    float th  = tt * 0.1f;
    float tif = rintf(th);

    // selective f64 recompute near round() boundaries (chaos control)
    if (fabsf(th - tif) < 1e-3f && tt < 120.0f) {
      const float* xr_u = upstream   + (size_t)(row0 + r) * TT;
      const float* xr_d = downstream + (size_t)(row0 + r) * TT;
      double xu64 = vel_branch64(xr_u, v11_w, v11_b, ln11_g, ln11_b, v12_w, v12_b[0]);
      double xd64 = vel_branch64(xr_d, v21_w, v21_b, ln21_g, ln21_b, v22_w, v22_b[0]);
      double y64  = xu64*(double)w3a + xd64*(double)w3b + (double)v3_b[0];
      double v64  = log1p(exp(y64));
      double tt64 = (double)dist / (v64 + 1e-5);
      v   = (float)v64;
      tt  = (float)tt64;
      tif = (float)rint(tt64 * 0.1);
    }

    int ti = (int)tif;
    ti = ti < 0 ? 0 : (ti > TT ? TT - 1 : ti);
    int n = TT - ti; n = n < 1 ? 1 : n;

    float Fk = 1.f / fmaf(al, tt, 1.f);
    float om = 1.f - Fk;

    float4 g0 = F[r*3], g1 = F[r*3+1], g2 = F[r*3+2];
    float feat[TT] = {g0.x,g0.y,g0.z,g0.w, g1.x,g1.y,g1.z,g1.w, g2.x,g2.y,g2.z,g2.w};
    float accf = 0.f;
#pragma unroll
    for (int t = 0; t < TT; ++t) {
      accf = (t < n) ? fmaf(accf, om, feat[t]) : accf;
    }
    float pe = Fk * accf;

    float4 nps = np_s[r], npd = np_d[r];
    float sum   = nps.x + npd.x + v;
    float sumsq = nps.y + npd.y + v*v;
    float mu  = sum * (1.f/129.f);
    float var = sumsq * (1.f/129.f) - mu*mu;
    float S1  = nps.z + npd.w + v * aw128;
    float aa  = (S1 - mu*sc0) / sqrtf(var + 1e-5f) + sc1;
    float a   = aa >= 0.f ? aa : 0.01f*aa;
    exv[r] = __expf(a);
    pev[r] = pe;
    atomicAdd(&den[s * TB + b0 + r], exv[r]);
  }

  float4 e0 = make_float4(exv[0], pev[0], exv[1], pev[1]);
  float4 e1 = make_float4(exv[2], pev[2], exv[3], pev[3]);
  ((float4*)epbuf)[idx*2]     = e0;
  ((float4*)epbuf)[idx*2 + 1] = e1;
}

// ---------- K3: normalize + scatter to pred ----------
__global__ void __launch_bounds__(256) k_edge2(
    const int* __restrict__ src, const int* __restrict__ dst,
    const float2* __restrict__ epbuf,
    const float* __restrict__ den, float* __restrict__ pred, int n_edges) {
  int idx = blockIdx.x * blockDim.x + threadIdx.x;
  if (idx >= n_edges * TB) return;
  int e = idx >> 3, b = idx & 7;
  float2 ep = epbuf[idx];
  float score = ep.x / den[src[e] * TB + b];
  atomicAdd(&pred[dst[e] * TB + b], score * ep.y);
}

extern "C" void kernel_launch(void* const* d_in, const int* in_sizes, int n_in,
                              void* d_out, int out_size, void* d_ws, size_t ws_size,
                              hipStream_t stream) {
  const float* upstream   = (const float*)d_in[0];
  const float* downstream = (const float*)d_in[1];
  const float* feature    = (const float*)d_in[2];
  const float* distance   = (const float*)d_in[3];
  const int*   src        = (const int*)d_in[4];
  const int*   dst        = (const int*)d_in[5];
  const float* fc_w   = (const float*)d_in[6];
  const float* attn_w = (const float*)d_in[7];
  const float* ln2_g  = (const float*)d_in[8];
  const float* ln2_b  = (const float*)d_in[9];
  const float* v11_w  = (const float*)d_in[10];
  const float* v11_b  = (const float*)d_in[11];
  const float* ln11_g = (const float*)d_in[12];
  const float* ln11_b = (const float*)d_in[13];
  const float* v12_w  = (const float*)d_in[14];
  const float* v12_b  = (const float*)d_in[15];
  const float* v21_w  = (const float*)d_in[16];
  const float* v21_b  = (const float*)d_in[17];
  const float* ln21_g = (const float*)d_in[18];
  const float* ln21_b = (const float*)d_in[19];
  const float* v22_w  = (const float*)d_in[20];
  const float* v22_b  = (const float*)d_in[21];
  const float* v3_w   = (const float*)d_in[22];
  const float* v3_b   = (const float*)d_in[23];
  const float* alpha  = (const float*)d_in[24];

  int E  = in_sizes[4];
  int N  = in_sizes[2] / (TB * TT);
  int NB = N * TB;
  int EB = E * TB;
  int NQ = EB / 4;   // 4-row quads

  float*  ws      = (float*)d_ws;
  float*  foldbuf = ws;                                   // 1344 floats
  float4* nodepre = (float4*)(ws + 1344);                 // 4*NB floats
  float2* epbuf   = (float2*)(ws + 1344 + 4 * (size_t)NB); // 2*EB floats
  float*  den     = ws + 1344 + 4 * (size_t)NB + 2 * (size_t)EB; // NB floats
  float*  scal    = den + NB;                             // 2 floats
  float*  pred    = (float*)d_out;                        // NB floats

  int blk = 256;
  k_fold<<<2, blk, 0, stream>>>(v11_w, v11_b, ln11_g, ln11_b, v12_w,
                                v21_w, v21_b, ln21_g, ln21_b, v22_w, foldbuf);
  k_zero_prep<<<(NB + blk - 1) / blk, blk, 0, stream>>>(den, pred, NB, attn_w, ln2_g, ln2_b, scal);
  k_node<<<(NB + blk - 1) / blk, blk, 0, stream>>>(feature, fc_w, attn_w, ln2_g, nodepre, N);
  k_edge1<<<(NQ + blk - 1) / blk, blk, 0, stream>>>(
      upstream, downstream, feature, distance, src, dst,
      attn_w, ln2_g,
      v11_w, v11_b, ln11_g, ln11_b, v12_w, v12_b,
      v21_w, v21_b, ln21_g, ln21_b, v22_w, v22_b,
      v3_w, v3_b, alpha,
      foldbuf, nodepre, scal, epbuf, den, NQ);
  k_edge2<<<(EB + blk - 1) / blk, blk, 0, stream>>>(src, dst, epbuf, den, pred, E);
}

// Round 6
// 199.507 us; speedup vs baseline: 1.4083x; 1.4083x over previous
//
#include <hip/hip_runtime.h>
#include <math.h>

#define TB 8    // BATCH
#define TT 12   // T_IN
#define HV 32   // H_VEL

typedef float v2f __attribute__((ext_vector_type(2)));

// packed per-branch weight layout (512 floats):
// [0..384) w1 (32 rows x 12), [384..416) b1, [416..448) g, [448..480) bn, [480..512) w2
#define PK_W1 0
#define PK_B1 384
#define PK_G  416
#define PK_BN 448
#define PK_W2 480

// ---------- f32 velocity branch, weights from LDS, t-packed + j-paired ----------
__device__ __forceinline__ float vel_branch32(const v2f xv[6], const float* swb, float b2) {
  const float* w1 = swb + PK_W1;
  const float* b1 = swb + PK_B1;
  const float* g  = swb + PK_G;
  const float* bn = swb + PK_BN;
  const float* w2 = swb + PK_W2;
  v2f h2[HV/2];
  v2f s1v = {0.f, 0.f}, s2v = {0.f, 0.f};
#pragma unroll
  for (int jp = 0; jp < HV/2; ++jp) {
    const float* w0  = w1 + (2*jp)   * TT;
    const float* w1r = w1 + (2*jp+1) * TT;
    v2f p0 = {0.f, 0.f}, p1 = {0.f, 0.f};
#pragma unroll
    for (int k = 0; k < 6; ++k) {
      p0 = __builtin_elementwise_fma(xv[k], *(const v2f*)(w0  + 2*k), p0);
      p1 = __builtin_elementwise_fma(xv[k], *(const v2f*)(w1r + 2*k), p1);
    }
    v2f bj = *(const v2f*)(b1 + 2*jp);
    v2f hv = {p0.x + p0.y + bj.x, p1.x + p1.y + bj.y};
    h2[jp] = hv;
    s1v += hv;
    s2v = __builtin_elementwise_fma(hv, hv, s2v);
  }
  float s1 = s1v.x + s1v.y;
  float s2 = s2v.x + s2v.y;
  float mu  = s1 * (1.f/HV);
  float var = s2 * (1.f/HV) - mu*mu;
  float inv = 1.f / sqrtf(var + 1e-5f);
  v2f mu2  = {mu, mu};
  v2f inv2 = {inv, inv};
  v2f zero = {0.f, 0.f};
  v2f acc2 = {b2, 0.f};
#pragma unroll
  for (int jp = 0; jp < HV/2; ++jp) {
    v2f gv  = *(const v2f*)(g  + 2*jp);
    v2f bnv = *(const v2f*)(bn + 2*jp);
    v2f w2v = *(const v2f*)(w2 + 2*jp);
    v2f yl = __builtin_elementwise_fma((h2[jp] - mu2) * inv2, gv, bnv);
    yl = __builtin_elementwise_max(yl, zero);
    acc2 = __builtin_elementwise_fma(yl, w2v, acc2);
  }
  float acc = acc2.x + acc2.y;
  return 1.f / (1.f + __expf(-acc));
}

// ---------- f64 velocity branch (cold-path kernel only) ----------
__device__ double vel_branch64(const float* x,
    const float* __restrict__ w1, const float* __restrict__ b1,
    const float* __restrict__ g,  const float* __restrict__ bn,
    const float* __restrict__ w2, float b2) {
  double s1 = 0.0, s2 = 0.0;
  for (int j = 0; j < HV; ++j) {
    double hj = (double)b1[j];
    for (int t = 0; t < TT; ++t) hj = fma((double)x[t], (double)w1[j*TT+t], hj);
    s1 += hj;
    s2 = fma(hj, hj, s2);
  }
  double mu  = s1 / (double)HV;
  double var = s2 / (double)HV - mu*mu;
  double inv = 1.0 / sqrt(var + 1e-5);
  double acc = (double)b2;
  for (int j = 0; j < HV; ++j) {
    double hj = (double)b1[j];
    for (int t = 0; t < TT; ++t) hj = fma((double)x[t], (double)w1[j*TT+t], hj);
    double yl = (hj - mu) * inv * (double)g[j] + (double)bn[j];
    if (yl < 0.0) yl = 0.0;
    acc = fma(yl, (double)w2[j], acc);
  }
  return 1.0 / (1.0 + exp(-acc));
}

// ---------- K_fold: pack raw weights into contiguous 2x512-float buffer ----------
__global__ void __launch_bounds__(256) k_fold(
    const float* __restrict__ v11_w, const float* __restrict__ v11_b,
    const float* __restrict__ ln11_g, const float* __restrict__ ln11_b,
    const float* __restrict__ v12_w,
    const float* __restrict__ v21_w, const float* __restrict__ v21_b,
    const float* __restrict__ ln21_g, const float* __restrict__ ln21_b,
    const float* __restrict__ v22_w,
    float* __restrict__ pack) {
  int br = blockIdx.x;
  const float* W1 = br ? v21_w : v11_w;
  const float* B1 = br ? v21_b : v11_b;
  const float* G  = br ? ln21_g : ln11_g;
  const float* BN = br ? ln21_b : ln11_b;
  const float* W2 = br ? v22_w : v12_w;
  float* p = pack + br * 512;
  for (int i = threadIdx.x; i < 512; i += blockDim.x) {
    float val;
    if (i < PK_B1)      val = W1[i];
    else if (i < PK_G)  val = B1[i - PK_B1];
    else if (i < PK_BN) val = G[i - PK_G];
    else if (i < PK_W2) val = BN[i - PK_BN];
    else                val = W2[i - PK_W2];
    p[i] = val;
  }
}

// ---------- K0: zero den+pred+fixcnt, block 0 reduces attention scalars ----------
__global__ void __launch_bounds__(256) k_zero_prep(
    float* __restrict__ den, float* __restrict__ pred, int nb,
    const float* __restrict__ attn_w, const float* __restrict__ ln2_g,
    const float* __restrict__ ln2_b, float* __restrict__ scal,
    int* __restrict__ fixcnt) {
  int idx = blockIdx.x * blockDim.x + threadIdx.x;
  for (int i = idx; i < nb; i += gridDim.x * blockDim.x) { den[i] = 0.f; pred[i] = 0.f; }
  if (blockIdx.x == 0) {
    if (threadIdx.x == 0) fixcnt[0] = 0;
    __shared__ float sg[256], sb[256];
    float a = 0.f, b = 0.f;
    if (threadIdx.x < 129) {
      float w = attn_w[threadIdx.x];
      a = w * ln2_g[threadIdx.x];
      b = w * ln2_b[threadIdx.x];
    }
    sg[threadIdx.x] = a; sb[threadIdx.x] = b;
    __syncthreads();
    for (int s = 128; s > 0; s >>= 1) {
      if (threadIdx.x < s) { sg[threadIdx.x] += sg[threadIdx.x+s]; sb[threadIdx.x] += sb[threadIdx.x+s]; }
      __syncthreads();
    }
    if (threadIdx.x == 0) { scal[0] = sg[0]; scal[1] = sb[0]; }
  }
}

// ---------- K1: per-(node,batch) precompute {Sz, Sz2, p_src, p_dst} ----------
__global__ void __launch_bounds__(256, 2) k_node(
    const float* __restrict__ feature, const float* __restrict__ fc_w,
    const float* __restrict__ attn_w,  const float* __restrict__ ln2_g,
    float4* __restrict__ nodepre, int n_nodes) {
  int idx = blockIdx.x * blockDim.x + threadIdx.x;
  int total = n_nodes * TB;
  if (idx >= total) return;
  const float4* f4 = (const float4*)(feature + (size_t)idx * TT);
  float4 fa = f4[0], fb = f4[1], fcv = f4[2];
  v2f xv[6] = {{fa.x,fa.y},{fa.z,fa.w},{fb.x,fb.y},{fb.z,fb.w},{fcv.x,fcv.y},{fcv.z,fcv.w}};
  float q = 0.f, r = 0.f, ps = 0.f, pd = 0.f;
#pragma unroll 8
  for (int i = 0; i < 64; ++i) {
    v2f p = {0.f, 0.f};
#pragma unroll
    for (int k = 0; k < 6; ++k)
      p = __builtin_elementwise_fma(xv[k], *(const v2f*)(fc_w + i*TT + 2*k), p);
    float z = p.x + p.y;
    q += z;
    r  = fmaf(z, z, r);
    ps = fmaf(z, attn_w[i]      * ln2_g[i],      ps);
    pd = fmaf(z, attn_w[64 + i] * ln2_g[64 + i], pd);
  }
  nodepre[idx] = make_float4(q, r, ps, pd);
}

// ---------- K2: fused edge pass, weights in LDS, f64 repair deferred ----------
__global__ void __launch_bounds__(256, 2) k_edge1(
    const float* __restrict__ upstream, const float* __restrict__ downstream,
    const float* __restrict__ feature,  const float* __restrict__ distance,
    const int* __restrict__ src, const int* __restrict__ dst,
    const float* __restrict__ attn_w, const float* __restrict__ ln2_g,
    const float* __restrict__ v12_b, const float* __restrict__ v22_b,
    const float* __restrict__ v3_w, const float* __restrict__ v3_b,
    const float* __restrict__ alpha,
    const float* __restrict__ pack,
    const float4* __restrict__ nodepre, const float* __restrict__ scal,
    float2* __restrict__ epbuf, float* __restrict__ den,
    int* __restrict__ fixcnt, int* __restrict__ fixlist, int fixcap,
    int n_edges) {
  __shared__ float sw[1024];
  // cooperative weight stage: exactly one float4 per thread
  ((float4*)sw)[threadIdx.x] = ((const float4*)pack)[threadIdx.x];
  __syncthreads();

  int idx = blockIdx.x * blockDim.x + threadIdx.x;
  if (idx >= n_edges * TB) return;
  int e = idx >> 3, b = idx & 7;

  // --- issue all random gathers early ---
  int s = src[e], d = dst[e];
  float dist = distance[e];
  float al   = alpha[e];
  const float4* f4 = (const float4*)(feature + ((size_t)s * TB + b) * TT);
  float4 f0 = f4[0], f1 = f4[1], f2 = f4[2];
  float4 nps = nodepre[(size_t)s * TB + b];
  float4 npd = nodepre[(size_t)d * TB + b];

  float xu, xd;
  {
    const float4* u4 = (const float4*)(upstream + (size_t)idx * TT);
    float4 a0 = u4[0], a1 = u4[1], a2 = u4[2];
    v2f xv[6] = {{a0.x,a0.y},{a0.z,a0.w},{a1.x,a1.y},{a1.z,a1.w},{a2.x,a2.y},{a2.z,a2.w}};
    xu = vel_branch32(xv, sw, v12_b[0]);
  }
  {
    const float4* d4 = (const float4*)(downstream + (size_t)idx * TT);
    float4 c0 = d4[0], c1 = d4[1], c2 = d4[2];
    v2f xv[6] = {{c0.x,c0.y},{c0.z,c0.w},{c1.x,c1.y},{c1.z,c1.w},{c2.x,c2.y},{c2.z,c2.w}};
    xd = vel_branch32(xv, sw + 512, v22_b[0]);
  }
  float y = fmaf(xu, v3_w[0], fmaf(xd, v3_w[1], v3_b[0]));
  // softplus via hardware exp/log: log1p(e^y) = max(y,0) + log(1 + e^-|y|)
  float v = fmaxf(y, 0.f) + __logf(1.f + __expf(-fabsf(y)));

  float tt  = dist / (v + 1e-5f);
  float th  = tt * 0.1f;
  float tif = rintf(th);

  // boundary rows: append to fixlist, repaired in f64 by k_fix before k_edge2
  if (fabsf(th - tif) < 1e-3f && tt < 120.0f) {
    int p = atomicAdd(fixcnt, 1);
    if (p < fixcap) fixlist[p] = idx;
  }

  int ti = (int)tif;
  ti = ti < 0 ? 0 : (ti > TT ? TT - 1 : ti);
  int n = TT - ti; n = n < 1 ? 1 : n;

  float F  = 1.f / fmaf(al, tt, 1.f);
  float om = 1.f - F;

  float feat[TT] = {f0.x,f0.y,f0.z,f0.w, f1.x,f1.y,f1.z,f1.w, f2.x,f2.y,f2.z,f2.w};
  float acc = 0.f;
#pragma unroll
  for (int t = 0; t < TT; ++t) {
    acc = (t < n) ? fmaf(acc, om, feat[t]) : acc;
  }
  float pe = F * acc;

  float sum   = nps.x + npd.x + v;
  float sumsq = nps.y + npd.y + v*v;
  float mu  = sum * (1.f/129.f);
  float var = sumsq * (1.f/129.f) - mu*mu;
  float S1  = nps.z + npd.w + v * attn_w[128] * ln2_g[128];
  float aa  = (S1 - mu*scal[0]) / sqrtf(var + 1e-5f) + scal[1];
  float a   = aa >= 0.f ? aa : 0.01f*aa;
  float ex  = __expf(a);

  epbuf[idx] = make_float2(ex, pe);
  atomicAdd(&den[s * TB + b], ex);
}

// ---------- K_fix: f64 recompute of boundary rows, delta-correct den/epbuf ----------
__global__ void __launch_bounds__(256) k_fix(
    const float* __restrict__ upstream, const float* __restrict__ downstream,
    const float* __restrict__ feature,  const float* __restrict__ distance,
    const int* __restrict__ src, const int* __restrict__ dst,
    const float* __restrict__ attn_w, const float* __restrict__ ln2_g,
    const float* __restrict__ v11_w, const float* __restrict__ v11_b,
    const float* __restrict__ ln11_g, const float* __restrict__ ln11_b,
    const float* __restrict__ v12_w, const float* __restrict__ v12_b,
    const float* __restrict__ v21_w, const float* __restrict__ v21_b,
    const float* __restrict__ ln21_g, const float* __restrict__ ln21_b,
    const float* __restrict__ v22_w, const float* __restrict__ v22_b,
    const float* __restrict__ v3_w, const float* __restrict__ v3_b,
    const float* __restrict__ alpha,
    const float4* __restrict__ nodepre, const float* __restrict__ scal,
    float2* __restrict__ epbuf, float* __restrict__ den,
    const int* __restrict__ fixcnt, const int* __restrict__ fixlist, int fixcap) {
  int cnt = fixcnt[0];
  if (cnt > fixcap) cnt = fixcap;
  int stride = gridDim.x * blockDim.x;
  for (int i = blockIdx.x * blockDim.x + threadIdx.x; i < cnt; i += stride) {
    int idx = fixlist[i];
    int e = idx >> 3, b = idx & 7;
    int s = src[e], d = dst[e];
    float dist = distance[e];
    float al   = alpha[e];

    const float* xr_u = upstream   + (size_t)idx * TT;
    const float* xr_d = downstream + (size_t)idx * TT;
    double xu64 = vel_branch64(xr_u, v11_w, v11_b, ln11_g, ln11_b, v12_w, v12_b[0]);
    double xd64 = vel_branch64(xr_d, v21_w, v21_b, ln21_g, ln21_b, v22_w, v22_b[0]);
    double y64  = xu64*(double)v3_w[0] + xd64*(double)v3_w[1] + (double)v3_b[0];
    double v64  = log1p(exp(y64));
    double tt64 = (double)dist / (v64 + 1e-5);
    float v   = (float)v64;
    float tt  = (float)tt64;
    float tif = (float)rint(tt64 * 0.1);

    int ti = (int)tif;
    ti = ti < 0 ? 0 : (ti > TT ? TT - 1 : ti);
    int n = TT - ti; n = n < 1 ? 1 : n;

    float F  = 1.f / fmaf(al, tt, 1.f);
    float om = 1.f - F;

    const float* feat = feature + ((size_t)s * TB + b) * TT;
    float acc = 0.f;
    for (int t = 0; t < n; ++t) acc = fmaf(acc, om, feat[t]);
    float pe = F * acc;

    float4 nps = nodepre[(size_t)s * TB + b];
    float4 npd = nodepre[(size_t)d * TB + b];
    float sum   = nps.x + npd.x + v;
    float sumsq = nps.y + npd.y + v*v;
    float mu  = sum * (1.f/129.f);
    float var = sumsq * (1.f/129.f) - mu*mu;
    float S1  = nps.z + npd.w + v * attn_w[128] * ln2_g[128];
    float aa  = (S1 - mu*scal[0]) / sqrtf(var + 1e-5f) + scal[1];
    float a   = aa >= 0.f ? aa : 0.01f*aa;
    float ex  = __expf(a);

    float2 old = epbuf[idx];
    epbuf[idx] = make_float2(ex, pe);
    atomicAdd(&den[s * TB + b], ex - old.x);
  }
}

// ---------- K3: normalize + scatter to pred ----------
__global__ void __launch_bounds__(256) k_edge2(
    const int* __restrict__ src, const int* __restrict__ dst,
    const float2* __restrict__ epbuf,
    const float* __restrict__ den, float* __restrict__ pred, int n_edges) {
  int idx = blockIdx.x * blockDim.x + threadIdx.x;
  if (idx >= n_edges * TB) return;
  int e = idx >> 3, b = idx & 7;
  float2 ep = epbuf[idx];
  float score = ep.x / den[src[e] * TB + b];
  atomicAdd(&pred[dst[e] * TB + b], score * ep.y);
}

extern "C" void kernel_launch(void* const* d_in, const int* in_sizes, int n_in,
                              void* d_out, int out_size, void* d_ws, size_t ws_size,
                              hipStream_t stream) {
  const float* upstream   = (const float*)d_in[0];
  const float* downstream = (const float*)d_in[1];
  const float* feature    = (const float*)d_in[2];
  const float* distance   = (const float*)d_in[3];
  const int*   src        = (const int*)d_in[4];
  const int*   dst        = (const int*)d_in[5];
  const float* fc_w   = (const float*)d_in[6];
  const float* attn_w = (const float*)d_in[7];
  const float* ln2_g  = (const float*)d_in[8];
  const float* ln2_b  = (const float*)d_in[9];
  const float* v11_w  = (const float*)d_in[10];
  const float* v11_b  = (const float*)d_in[11];
  const float* ln11_g = (const float*)d_in[12];
  const float* ln11_b = (const float*)d_in[13];
  const float* v12_w  = (const float*)d_in[14];
  const float* v12_b  = (const float*)d_in[15];
  const float* v21_w  = (const float*)d_in[16];
  const float* v21_b  = (const float*)d_in[17];
  const float* ln21_g = (const float*)d_in[18];
  const float* ln21_b = (const float*)d_in[19];
  const float* v22_w  = (const float*)d_in[20];
  const float* v22_b  = (const float*)d_in[21];
  const float* v3_w   = (const float*)d_in[22];
  const float* v3_b   = (const float*)d_in[23];
  const float* alpha  = (const float*)d_in[24];

  int E  = in_sizes[4];
  int N  = in_sizes[2] / (TB * TT);
  int NB = N * TB;
  int EB = E * TB;
  int fixcap = EB / 4;

  float*  ws      = (float*)d_ws;
  float4* nodepre = (float4*)ws;                            // 4*NB floats
  float2* epbuf   = (float2*)(ws + 4 * (size_t)NB);         // 2*EB floats
  float*  den     = ws + 4 * (size_t)NB + 2 * (size_t)EB;   // NB floats
  float*  scal    = den + NB;                               // 2 floats
  float*  pack    = scal + 2;                               // 1024 floats
  int*    fixcnt  = (int*)(pack + 1024);                    // 4 ints (1 used)
  int*    fixlist = fixcnt + 4;                             // fixcap ints
  float*  pred    = (float*)d_out;                          // NB floats

  int blk = 256;
  k_fold<<<2, blk, 0, stream>>>(v11_w, v11_b, ln11_g, ln11_b, v12_w,
                                v21_w, v21_b, ln21_g, ln21_b, v22_w, pack);
  k_zero_prep<<<(NB + blk - 1) / blk, blk, 0, stream>>>(den, pred, NB, attn_w, ln2_g, ln2_b, scal, fixcnt);
  k_node<<<(NB + blk - 1) / blk, blk, 0, stream>>>(feature, fc_w, attn_w, ln2_g, nodepre, N);
  k_edge1<<<(EB + blk - 1) / blk, blk, 0, stream>>>(
      upstream, downstream, feature, distance, src, dst,
      attn_w, ln2_g, v12_b, v22_b, v3_w, v3_b, alpha,
      pack, nodepre, scal, epbuf, den, fixcnt, fixlist, fixcap, E);
  k_fix<<<64, blk, 0, stream>>>(
      upstream, downstream, feature, distance, src, dst,
      attn_w, ln2_g,
      v11_w, v11_b, ln11_g, ln11_b, v12_w, v12_b,
      v21_w, v21_b, ln21_g, ln21_b, v22_w, v22_b,
      v3_w, v3_b, alpha,
      nodepre, scal, epbuf, den, fixcnt, fixlist, fixcap);
  k_edge2<<<(EB + blk - 1) / blk, blk, 0, stream>>>(src, dst, epbuf, den, pred, E);
}

// Round 7
// 169.383 us; speedup vs baseline: 1.6588x; 1.1778x over previous
//
#include <hip/hip_runtime.h>
#include <math.h>

#define TB 8    // BATCH
#define TT 12   // T_IN
#define HV 32   // H_VEL

typedef float v2f __attribute__((ext_vector_type(2)));

// packed per-branch weight layout (576 floats, stride 576):
// [0..384)   W1: row j at j*12 (row PAIR 2jp,2jp+1 = 24 floats = 6 float4, 16B aligned)
// [384..416) b1
// [416..544) TL[16][8] = {g0,g1,bn0,bn1,w20,w21,0,0} per jp
// [544..576) pad
#define PK_B1 384
#define PK_TL 416
#define PK_STRIDE 576

// ---------- f32 velocity branch, weights from LDS via b128 reads ----------
__device__ __forceinline__ float vel_branch32(const v2f xv[6], const float* swb, float b2) {
  v2f h2[16];
  v2f s1v = {0.f, 0.f}, s2v = {0.f, 0.f};
#pragma unroll
  for (int jp = 0; jp < 16; ++jp) {
    const float4* wr = (const float4*)(swb + jp * 24);
    float4 a0 = wr[0], a1 = wr[1], a2 = wr[2];
    float4 c0 = wr[3], c1 = wr[4], c2 = wr[5];
    v2f bj = *(const v2f*)(swb + PK_B1 + 2*jp);
    v2f p0 = xv[0] * (v2f){a0.x, a0.y};
    p0 = __builtin_elementwise_fma(xv[1], (v2f){a0.z, a0.w}, p0);
    p0 = __builtin_elementwise_fma(xv[2], (v2f){a1.x, a1.y}, p0);
    p0 = __builtin_elementwise_fma(xv[3], (v2f){a1.z, a1.w}, p0);
    p0 = __builtin_elementwise_fma(xv[4], (v2f){a2.x, a2.y}, p0);
    p0 = __builtin_elementwise_fma(xv[5], (v2f){a2.z, a2.w}, p0);
    v2f p1 = xv[0] * (v2f){c0.x, c0.y};
    p1 = __builtin_elementwise_fma(xv[1], (v2f){c0.z, c0.w}, p1);
    p1 = __builtin_elementwise_fma(xv[2], (v2f){c1.x, c1.y}, p1);
    p1 = __builtin_elementwise_fma(xv[3], (v2f){c1.z, c1.w}, p1);
    p1 = __builtin_elementwise_fma(xv[4], (v2f){c2.x, c2.y}, p1);
    p1 = __builtin_elementwise_fma(xv[5], (v2f){c2.z, c2.w}, p1);
    v2f hv = { p0.x + p0.y + bj.x, p1.x + p1.y + bj.y };
    h2[jp] = hv;
    s1v += hv;
    s2v = __builtin_elementwise_fma(hv, hv, s2v);
  }
  float s1 = s1v.x + s1v.y;
  float s2 = s2v.x + s2v.y;
  float mu  = s1 * (1.f/HV);
  float var = s2 * (1.f/HV) - mu*mu;
  float inv = 1.f / sqrtf(var + 1e-5f);
  v2f mu2  = {mu, mu};
  v2f inv2 = {inv, inv};
  v2f zero = {0.f, 0.f};
  v2f acc2 = {b2, 0.f};
#pragma unroll
  for (int jp = 0; jp < 16; ++jp) {
    float4 t0 = *(const float4*)(swb + PK_TL + 8*jp);
    v2f w2v   = *(const v2f*)(swb + PK_TL + 8*jp + 4);
    v2f gv  = {t0.x, t0.y};
    v2f bnv = {t0.z, t0.w};
    v2f yl = __builtin_elementwise_fma((h2[jp] - mu2) * inv2, gv, bnv);
    yl = __builtin_elementwise_max(yl, zero);
    acc2 = __builtin_elementwise_fma(yl, w2v, acc2);
  }
  return 1.f / (1.f + __expf(-(acc2.x + acc2.y)));
}

// ---------- f64 velocity branch (cold-path kernel only) ----------
__device__ double vel_branch64(const float* x,
    const float* __restrict__ w1, const float* __restrict__ b1,
    const float* __restrict__ g,  const float* __restrict__ bn,
    const float* __restrict__ w2, float b2) {
  double s1 = 0.0, s2 = 0.0;
  for (int j = 0; j < HV; ++j) {
    double hj = (double)b1[j];
    for (int t = 0; t < TT; ++t) hj = fma((double)x[t], (double)w1[j*TT+t], hj);
    s1 += hj;
    s2 = fma(hj, hj, s2);
  }
  double mu  = s1 / (double)HV;
  double var = s2 / (double)HV - mu*mu;
  double inv = 1.0 / sqrt(var + 1e-5);
  double acc = (double)b2;
  for (int j = 0; j < HV; ++j) {
    double hj = (double)b1[j];
    for (int t = 0; t < TT; ++t) hj = fma((double)x[t], (double)w1[j*TT+t], hj);
    double yl = (hj - mu) * inv * (double)g[j] + (double)bn[j];
    if (yl < 0.0) yl = 0.0;
    acc = fma(yl, (double)w2[j], acc);
  }
  return 1.0 / (1.0 + exp(-acc));
}

// ---------- K_prep: zero den/pred/fixcnt; block0 folds scalars; blocks1-2 pack weights ----------
__global__ void __launch_bounds__(256) k_prep(
    float* __restrict__ den, float* __restrict__ pred, int nb,
    const float* __restrict__ attn_w, const float* __restrict__ ln2_g,
    const float* __restrict__ ln2_b,
    const float* __restrict__ v11_w, const float* __restrict__ v11_b,
    const float* __restrict__ ln11_g, const float* __restrict__ ln11_b,
    const float* __restrict__ v12_w, const float* __restrict__ v12_b,
    const float* __restrict__ v21_w, const float* __restrict__ v21_b,
    const float* __restrict__ ln21_g, const float* __restrict__ ln21_b,
    const float* __restrict__ v22_w, const float* __restrict__ v22_b,
    const float* __restrict__ v3_w, const float* __restrict__ v3_b,
    float* __restrict__ scal, float* __restrict__ pack, int* __restrict__ fixcnt) {
  int idx = blockIdx.x * blockDim.x + threadIdx.x;
  for (int i = idx; i < nb; i += gridDim.x * blockDim.x) { den[i] = 0.f; pred[i] = 0.f; }
  if (blockIdx.x == 0) {
    __shared__ float sg[256], sb[256];
    float a = 0.f, b = 0.f;
    if (threadIdx.x < 129) {
      float w = attn_w[threadIdx.x];
      a = w * ln2_g[threadIdx.x];
      b = w * ln2_b[threadIdx.x];
    }
    sg[threadIdx.x] = a; sb[threadIdx.x] = b;
    __syncthreads();
    for (int s = 128; s > 0; s >>= 1) {
      if (threadIdx.x < s) { sg[threadIdx.x] += sg[threadIdx.x+s]; sb[threadIdx.x] += sb[threadIdx.x+s]; }
      __syncthreads();
    }
    if (threadIdx.x == 0) {
      scal[0] = sg[0]; scal[1] = sb[0];
      scal[2] = attn_w[128] * ln2_g[128];
      scal[3] = v12_b[0];  scal[4] = v22_b[0];
      scal[5] = v3_w[0];   scal[6] = v3_w[1];  scal[7] = v3_b[0];
      fixcnt[0] = 0;
    }
  } else if (blockIdx.x <= 2) {
    int br = blockIdx.x - 1;
    const float* W1 = br ? v21_w : v11_w;
    const float* B1 = br ? v21_b : v11_b;
    const float* G  = br ? ln21_g : ln11_g;
    const float* BN = br ? ln21_b : ln11_b;
    const float* W2 = br ? v22_w : v12_w;
    float* p = pack + br * PK_STRIDE;
    for (int i = threadIdx.x; i < PK_STRIDE; i += 256) {
      float val = 0.f;
      if (i < PK_B1)      val = W1[i];
      else if (i < PK_TL) val = B1[i - PK_B1];
      else if (i < 544) {
        int q = i - PK_TL, jp = q >> 3, k = q & 7;
        int j = 2*jp + (k & 1);
        if (k < 2)      val = G[j];
        else if (k < 4) val = BN[j];
        else if (k < 6) val = W2[j];
      }
      p[i] = val;
    }
  }
}

// ---------- K1: per-(node,batch) precompute {Sz, Sz2, p_src, p_dst} ----------
__global__ void __launch_bounds__(256, 2) k_node(
    const float* __restrict__ feature, const float* __restrict__ fc_w,
    const float* __restrict__ attn_w,  const float* __restrict__ ln2_g,
    float4* __restrict__ nodepre, int n_nodes) {
  int idx = blockIdx.x * blockDim.x + threadIdx.x;
  int total = n_nodes * TB;
  if (idx >= total) return;
  const float4* f4 = (const float4*)(feature + (size_t)idx * TT);
  float4 fa = f4[0], fb = f4[1], fcv = f4[2];
  v2f xv[6] = {{fa.x,fa.y},{fa.z,fa.w},{fb.x,fb.y},{fb.z,fb.w},{fcv.x,fcv.y},{fcv.z,fcv.w}};
  float q = 0.f, r = 0.f, ps = 0.f, pd = 0.f;
#pragma unroll 8
  for (int i = 0; i < 64; ++i) {
    v2f p = {0.f, 0.f};
#pragma unroll
    for (int k = 0; k < 6; ++k)
      p = __builtin_elementwise_fma(xv[k], *(const v2f*)(fc_w + i*TT + 2*k), p);
    float z = p.x + p.y;
    q += z;
    r  = fmaf(z, z, r);
    ps = fmaf(z, attn_w[i]      * ln2_g[i],      ps);
    pd = fmaf(z, attn_w[64 + i] * ln2_g[64 + i], pd);
  }
  nodepre[idx] = make_float4(q, r, ps, pd);
}

// ---------- K2: fused edge pass, weights in LDS (b128 reads), f64 repair deferred ----------
__global__ void __launch_bounds__(256, 2) k_edge1(
    const float* __restrict__ upstream, const float* __restrict__ downstream,
    const float* __restrict__ feature,  const float* __restrict__ distance,
    const int* __restrict__ src, const int* __restrict__ dst,
    const float* __restrict__ alpha,
    const float* __restrict__ pack,
    const float4* __restrict__ nodepre, const float* __restrict__ scal,
    float2* __restrict__ epbuf, float* __restrict__ den,
    int* __restrict__ fixcnt, int* __restrict__ fixlist, int fixcap,
    int n_edges) {
  __shared__ float sw[2 * PK_STRIDE];
  for (int i = threadIdx.x; i < 2 * PK_STRIDE / 4; i += 256)
    ((float4*)sw)[i] = ((const float4*)pack)[i];
  __syncthreads();

  int idx = blockIdx.x * blockDim.x + threadIdx.x;
  if (idx >= n_edges * TB) return;
  int e = idx >> 3, b = idx & 7;

  // uniform folded scalars
  float sc0 = scal[0], sc1 = scal[1], aw128 = scal[2];
  float b2u = scal[3], b2d = scal[4];
  float w3a = scal[5], w3b = scal[6], b3 = scal[7];

  // --- issue all random gathers early ---
  int s = src[e], d = dst[e];
  float dist = distance[e];
  float al   = alpha[e];
  const float4* f4 = (const float4*)(feature + ((size_t)s * TB + b) * TT);
  float4 f0 = f4[0], f1 = f4[1], f2 = f4[2];
  float4 nps = nodepre[(size_t)s * TB + b];
  float4 npd = nodepre[(size_t)d * TB + b];

  float xu, xd;
  {
    const float4* u4 = (const float4*)(upstream + (size_t)idx * TT);
    float4 a0 = u4[0], a1 = u4[1], a2 = u4[2];
    v2f xv[6] = {{a0.x,a0.y},{a0.z,a0.w},{a1.x,a1.y},{a1.z,a1.w},{a2.x,a2.y},{a2.z,a2.w}};
    xu = vel_branch32(xv, sw, b2u);
  }
  {
    const float4* d4 = (const float4*)(downstream + (size_t)idx * TT);
    float4 c0 = d4[0], c1 = d4[1], c2 = d4[2];
    v2f xv[6] = {{c0.x,c0.y},{c0.z,c0.w},{c1.x,c1.y},{c1.z,c1.w},{c2.x,c2.y},{c2.z,c2.w}};
    xd = vel_branch32(xv, sw + PK_STRIDE, b2d);
  }
  float y = fmaf(xu, w3a, fmaf(xd, w3b, b3));
  // softplus via hardware exp/log: log1p(e^y) = max(y,0) + log(1 + e^-|y|)
  float v = fmaxf(y, 0.f) + __logf(1.f + __expf(-fabsf(y)));

  float tt  = dist / (v + 1e-5f);
  float th  = tt * 0.1f;
  float tif = rintf(th);

  // boundary rows (round() flips at HALF-integers): defer f64 repair to k_fix
  float frac = th - tif;   // in [-0.5, 0.5]
  if (fabsf(fabsf(frac) - 0.5f) < 2.5e-4f && th < 11.0f) {
    int p = atomicAdd(fixcnt, 1);
    if (p < fixcap) fixlist[p] = idx;
  }

  int ti = (int)tif;
  ti = ti < 0 ? 0 : (ti > TT ? TT - 1 : ti);
  int n = TT - ti; n = n < 1 ? 1 : n;

  float F  = 1.f / fmaf(al, tt, 1.f);
  float om = 1.f - F;

  float feat[TT] = {f0.x,f0.y,f0.z,f0.w, f1.x,f1.y,f1.z,f1.w, f2.x,f2.y,f2.z,f2.w};
  float acc = 0.f;
#pragma unroll
  for (int t = 0; t < TT; ++t) {
    acc = (t < n) ? fmaf(acc, om, feat[t]) : acc;
  }
  float pe = F * acc;

  float sum   = nps.x + npd.x + v;
  float sumsq = nps.y + npd.y + v*v;
  float mu  = sum * (1.f/129.f);
  float var = sumsq * (1.f/129.f) - mu*mu;
  float S1  = nps.z + npd.w + v * aw128;
  float aa  = (S1 - mu*sc0) / sqrtf(var + 1e-5f) + sc1;
  float a   = aa >= 0.f ? aa : 0.01f*aa;
  float ex  = __expf(a);

  epbuf[idx] = make_float2(ex, pe);
  atomicAdd(&den[s * TB + b], ex);
}

// ---------- K_fix: f64 recompute of boundary rows, delta-correct den/epbuf ----------
__global__ void __launch_bounds__(256) k_fix(
    const float* __restrict__ upstream, const float* __restrict__ downstream,
    const float* __restrict__ feature,  const float* __restrict__ distance,
    const int* __restrict__ src, const int* __restrict__ dst,
    const float* __restrict__ v11_w, const float* __restrict__ v11_b,
    const float* __restrict__ ln11_g, const float* __restrict__ ln11_b,
    const float* __restrict__ v12_w, const float* __restrict__ v12_b,
    const float* __restrict__ v21_w, const float* __restrict__ v21_b,
    const float* __restrict__ ln21_g, const float* __restrict__ ln21_b,
    const float* __restrict__ v22_w, const float* __restrict__ v22_b,
    const float* __restrict__ v3_w, const float* __restrict__ v3_b,
    const float* __restrict__ alpha,
    const float4* __restrict__ nodepre, const float* __restrict__ scal,
    float2* __restrict__ epbuf, float* __restrict__ den,
    const int* __restrict__ fixcnt, const int* __restrict__ fixlist, int fixcap) {
  int cnt = fixcnt[0];
  if (cnt > fixcap) cnt = fixcap;
  int stride = gridDim.x * blockDim.x;
  for (int i = blockIdx.x * blockDim.x + threadIdx.x; i < cnt; i += stride) {
    int idx = fixlist[i];
    int e = idx >> 3, b = idx & 7;
    int s = src[e], d = dst[e];
    float dist = distance[e];
    float al   = alpha[e];

    const float* xr_u = upstream   + (size_t)idx * TT;
    const float* xr_d = downstream + (size_t)idx * TT;
    double xu64 = vel_branch64(xr_u, v11_w, v11_b, ln11_g, ln11_b, v12_w, v12_b[0]);
    double xd64 = vel_branch64(xr_d, v21_w, v21_b, ln21_g, ln21_b, v22_w, v22_b[0]);
    double y64  = xu64*(double)v3_w[0] + xd64*(double)v3_w[1] + (double)v3_b[0];
    double v64  = log1p(exp(y64));
    double tt64 = (double)dist / (v64 + 1e-5);
    float v   = (float)v64;
    float tt  = (float)tt64;
    float tif = (float)rint(tt64 * 0.1);

    int ti = (int)tif;
    ti = ti < 0 ? 0 : (ti > TT ? TT - 1 : ti);
    int n = TT - ti; n = n < 1 ? 1 : n;

    float F  = 1.f / fmaf(al, tt, 1.f);
    float om = 1.f - F;

    const float* feat = feature + ((size_t)s * TB + b) * TT;
    float acc = 0.f;
    for (int t = 0; t < n; ++t) acc = fmaf(acc, om, feat[t]);
    float pe = F * acc;

    float4 nps = nodepre[(size_t)s * TB + b];
    float4 npd = nodepre[(size_t)d * TB + b];
    float sum   = nps.x + npd.x + v;
    float sumsq = nps.y + npd.y + v*v;
    float mu  = sum * (1.f/129.f);
    float var = sumsq * (1.f/129.f) - mu*mu;
    float S1  = nps.z + npd.w + v * scal[2];
    float aa  = (S1 - mu*scal[0]) / sqrtf(var + 1e-5f) + scal[1];
    float a   = aa >= 0.f ? aa : 0.01f*aa;
    float ex  = __expf(a);

    float2 old = epbuf[idx];
    epbuf[idx] = make_float2(ex, pe);
    atomicAdd(&den[s * TB + b], ex - old.x);
  }
}

// ---------- K3: normalize + scatter to pred ----------
__global__ void __launch_bounds__(256) k_edge2(
    const int* __restrict__ src, const int* __restrict__ dst,
    const float2* __restrict__ epbuf,
    const float* __restrict__ den, float* __restrict__ pred, int n_edges) {
  int idx = blockIdx.x * blockDim.x + threadIdx.x;
  if (idx >= n_edges * TB) return;
  int e = idx >> 3, b = idx & 7;
  float2 ep = epbuf[idx];
  float score = ep.x / den[src[e] * TB + b];
  atomicAdd(&pred[dst[e] * TB + b], score * ep.y);
}

extern "C" void kernel_launch(void* const* d_in, const int* in_sizes, int n_in,
                              void* d_out, int out_size, void* d_ws, size_t ws_size,
                              hipStream_t stream) {
  const float* upstream   = (const float*)d_in[0];
  const float* downstream = (const float*)d_in[1];
  const float* feature    = (const float*)d_in[2];
  const float* distance   = (const float*)d_in[3];
  const int*   src        = (const int*)d_in[4];
  const int*   dst        = (const int*)d_in[5];
  const float* fc_w   = (const float*)d_in[6];
  const float* attn_w = (const float*)d_in[7];
  const float* ln2_g  = (const float*)d_in[8];
  const float* ln2_b  = (const float*)d_in[9];
  const float* v11_w  = (const float*)d_in[10];
  const float* v11_b  = (const float*)d_in[11];
  const float* ln11_g = (const float*)d_in[12];
  const float* ln11_b = (const float*)d_in[13];
  const float* v12_w  = (const float*)d_in[14];
  const float* v12_b  = (const float*)d_in[15];
  const float* v21_w  = (const float*)d_in[16];
  const float* v21_b  = (const float*)d_in[17];
  const float* ln21_g = (const float*)d_in[18];
  const float* ln21_b = (const float*)d_in[19];
  const float* v22_w  = (const float*)d_in[20];
  const float* v22_b  = (const float*)d_in[21];
  const float* v3_w   = (const float*)d_in[22];
  const float* v3_b   = (const float*)d_in[23];
  const float* alpha  = (const float*)d_in[24];

  int E  = in_sizes[4];
  int N  = in_sizes[2] / (TB * TT);
  int NB = N * TB;
  int EB = E * TB;
  int fixcap = EB / 8;

  float*  ws      = (float*)d_ws;
  float4* nodepre = (float4*)ws;                            // 4*NB floats
  float2* epbuf   = (float2*)(ws + 4 * (size_t)NB);         // 2*EB floats
  float*  den     = ws + 4 * (size_t)NB + 2 * (size_t)EB;   // NB floats
  float*  scal    = den + NB;                               // 8 floats
  float*  pack    = scal + 8;                               // 1152 floats
  int*    fixcnt  = (int*)(pack + 2 * PK_STRIDE);           // 4 ints (1 used)
  int*    fixlist = fixcnt + 4;                             // fixcap ints
  float*  pred    = (float*)d_out;                          // NB floats

  int blk = 256;
  k_prep<<<(NB + blk - 1) / blk, blk, 0, stream>>>(
      den, pred, NB, attn_w, ln2_g, ln2_b,
      v11_w, v11_b, ln11_g, ln11_b, v12_w, v12_b,
      v21_w, v21_b, ln21_g, ln21_b, v22_w, v22_b,
      v3_w, v3_b, scal, pack, fixcnt);
  k_node<<<(NB + blk - 1) / blk, blk, 0, stream>>>(feature, fc_w, attn_w, ln2_g, nodepre, N);
  k_edge1<<<(EB + blk - 1) / blk, blk, 0, stream>>>(
      upstream, downstream, feature, distance, src, dst, alpha,
      pack, nodepre, scal, epbuf, den, fixcnt, fixlist, fixcap, E);
  k_fix<<<16, blk, 0, stream>>>(
      upstream, downstream, feature, distance, src, dst,
      v11_w, v11_b, ln11_g, ln11_b, v12_w, v12_b,
      v21_w, v21_b, ln21_g, ln21_b, v22_w, v22_b,
      v3_w, v3_b, alpha,
      nodepre, scal, epbuf, den, fixcnt, fixlist, fixcap);
  k_edge2<<<(EB + blk - 1) / blk, blk, 0, stream>>>(src, dst, epbuf, den, pred, E);
}